// Round 1
// baseline (43.504 us; speedup 1.0000x reference)
//
#include <hip/hip_runtime.h>
#include <math.h>

#define WAVES_PER_BLOCK 4

__device__ __forceinline__ float log_sigmoid(float x) {
    // log(sigmoid(x)) = min(x,0) - log1p(exp(-|x|)), numerically stable
    return fminf(x, 0.0f) - log1pf(__expf(-fabsf(x)));
}

__global__ __launch_bounds__(256) void cbow_partial_kernel(
    const int* __restrict__ context,      // (B, 10)
    const int* __restrict__ target,       // (B,)
    const int* __restrict__ neg_targets,  // (B, 10)
    const float* __restrict__ W_in,       // (V, 128)
    const float* __restrict__ W_out,      // (V, 128)
    float* __restrict__ partial,          // (gridDim.x,)
    int B)
{
    const int lane = threadIdx.x & 63;
    const int wave = threadIdx.x >> 6;
    const int b = blockIdx.x * WAVES_PER_BLOCK + wave;

    __shared__ float wsum[WAVES_PER_BLOCK];

    float loss = 0.0f;
    if (b < B) {
        const float2* __restrict__ Win2  = (const float2*)W_in;   // row stride 64 float2
        const float2* __restrict__ Wout2 = (const float2*)W_out;

        // h = mean of 10 context rows; lane holds dims [2*lane, 2*lane+1]
        float hx = 0.f, hy = 0.f;
        #pragma unroll
        for (int c = 0; c < 10; ++c) {
            const int idx = context[b * 10 + c];
            const float2 v = Win2[(size_t)idx * 64 + lane];
            hx += v.x; hy += v.y;
        }
        hx *= 0.1f; hy *= 0.1f;

        // 11 dot products: positive + 10 negatives
        float s[11];
        {
            const int idx = target[b];
            const float2 v = Wout2[(size_t)idx * 64 + lane];
            s[0] = hx * v.x + hy * v.y;
        }
        #pragma unroll
        for (int k = 0; k < 10; ++k) {
            const int idx = neg_targets[b * 10 + k];
            const float2 v = Wout2[(size_t)idx * 64 + lane];
            s[1 + k] = hx * v.x + hy * v.y;
        }

        // butterfly reduce all 11 partials across the 64-lane wave
        #pragma unroll
        for (int off = 32; off > 0; off >>= 1) {
            #pragma unroll
            for (int i = 0; i < 11; ++i)
                s[i] += __shfl_xor(s[i], off, 64);
        }

        loss = log_sigmoid(s[0]);
        #pragma unroll
        for (int k = 0; k < 10; ++k)
            loss += log_sigmoid(-s[1 + k]);
    }

    if (lane == 0) wsum[wave] = loss;
    __syncthreads();
    if (threadIdx.x == 0) {
        float t = 0.f;
        #pragma unroll
        for (int w = 0; w < WAVES_PER_BLOCK; ++w) t += wsum[w];
        partial[blockIdx.x] = t;
    }
}

__global__ __launch_bounds__(256) void reduce_partials_kernel(
    const float* __restrict__ partial, int n, float* __restrict__ out, float scale)
{
    __shared__ float sm[4];
    float t = 0.f;
    for (int i = threadIdx.x; i < n; i += 256) t += partial[i];
    #pragma unroll
    for (int off = 32; off > 0; off >>= 1) t += __shfl_xor(t, off, 64);
    const int lane = threadIdx.x & 63;
    const int wave = threadIdx.x >> 6;
    if (lane == 0) sm[wave] = t;
    __syncthreads();
    if (threadIdx.x == 0) {
        out[0] = (sm[0] + sm[1] + sm[2] + sm[3]) * scale;
    }
}

extern "C" void kernel_launch(void* const* d_in, const int* in_sizes, int n_in,
                              void* d_out, int out_size, void* d_ws, size_t ws_size,
                              hipStream_t stream) {
    const int* context     = (const int*)d_in[0];
    const int* target      = (const int*)d_in[1];
    const int* neg_targets = (const int*)d_in[2];
    const float* W_in      = (const float*)d_in[3];
    const float* W_out     = (const float*)d_in[4];
    float* out = (float*)d_out;

    const int B = in_sizes[1];                      // 16384
    const int nblocks = (B + WAVES_PER_BLOCK - 1) / WAVES_PER_BLOCK;  // 4096

    float* partial = (float*)d_ws;                  // nblocks floats of scratch

    cbow_partial_kernel<<<nblocks, 256, 0, stream>>>(
        context, target, neg_targets, W_in, W_out, partial, B);

    reduce_partials_kernel<<<1, 256, 0, stream>>>(
        partial, nblocks, out, -1.0f / (float)B);
}

// Round 2
// 34.190 us; speedup vs baseline: 1.2724x; 1.2724x over previous
//
#include <hip/hip_runtime.h>
#include <math.h>

#define WAVES_PER_BLOCK 4   // 256 threads; 2 elements per wave -> 8 elements/block

__device__ __forceinline__ float log_sigmoid_fast(float x) {
    // log(sigmoid(x)) = min(x,0) - log(1 + exp(-|x|))
    // __expf/__logf -> v_exp_f32/v_log_f32 (+1 mul each). |abs err| < 1e-6 absolute.
    return fminf(x, 0.0f) - __logf(1.0f + __expf(-fabsf(x)));
}

__global__ __launch_bounds__(256) void cbow_partial_kernel(
    const int* __restrict__ context,      // (B, 10)
    const int* __restrict__ target,       // (B,)
    const int* __restrict__ neg_targets,  // (B, 10)
    const float* __restrict__ W_in,       // (V, 128)
    const float* __restrict__ W_out,      // (V, 128)
    float* __restrict__ partial,          // (gridDim.x,)
    int B)
{
    const int lane = threadIdx.x & 63;
    const int wave = threadIdx.x >> 6;
    const int half = lane >> 5;          // which element of the pair
    const int l    = lane & 31;          // lane within 32-lane row group

    // each half-wave owns one batch element; lane l holds dims [4l, 4l+3]
    int b = (blockIdx.x * WAVES_PER_BLOCK + wave) * 2 + half;
    const bool valid = (b < B);
    if (b >= B) b = 0;   // clamp for safe addressing; loss masked below

    const float4* __restrict__ Win4  = (const float4*)W_in;   // row stride 32 float4
    const float4* __restrict__ Wout4 = (const float4*)W_out;

    // ---- load all 21 indices (uniform per half-wave; 1 line per half) ----
    int cidx[10], nidx[10], tidx;
    #pragma unroll
    for (int c = 0; c < 10; ++c) cidx[c] = context[b * 10 + c];
    tidx = target[b];
    #pragma unroll
    for (int k = 0; k < 10; ++k) nidx[k] = neg_targets[b * 10 + k];

    // ---- issue all 21 row gathers; keep them all in flight ----
    float4 cr[10];
    #pragma unroll
    for (int c = 0; c < 10; ++c) cr[c] = Win4[(size_t)cidx[c] * 32 + l];
    float4 orow[11];
    orow[0] = Wout4[(size_t)tidx * 32 + l];
    #pragma unroll
    for (int k = 0; k < 10; ++k) orow[1 + k] = Wout4[(size_t)nidx[k] * 32 + l];

    // ---- h = mean of context rows (consumes cr in issue order) ----
    float4 h = {0.f, 0.f, 0.f, 0.f};
    #pragma unroll
    for (int c = 0; c < 10; ++c) {
        h.x += cr[c].x; h.y += cr[c].y; h.z += cr[c].z; h.w += cr[c].w;
    }
    h.x *= 0.1f; h.y *= 0.1f; h.z *= 0.1f; h.w *= 0.1f;

    // ---- 11 dot-product partials ----
    float s[11];
    #pragma unroll
    for (int i = 0; i < 11; ++i) {
        const float4 v = orow[i];
        s[i] = h.x * v.x + h.y * v.y + h.z * v.z + h.w * v.w;
    }

    // ---- butterfly reduce within each 32-lane group (xor offs < 32 stay in-half) ----
    #pragma unroll
    for (int off = 16; off > 0; off >>= 1) {
        #pragma unroll
        for (int i = 0; i < 11; ++i)
            s[i] += __shfl_xor(s[i], off, 64);
    }

    // every lane now holds its element's 11 full dots
    float loss = log_sigmoid_fast(s[0]);
    #pragma unroll
    for (int k = 0; k < 10; ++k)
        loss += log_sigmoid_fast(-s[1 + k]);
    if (!valid) loss = 0.f;

    // combine the two half-wave elements: after this every lane has lossA+lossB
    loss += __shfl_xor(loss, 32, 64);

    __shared__ float wsum[WAVES_PER_BLOCK];
    if (lane == 0) wsum[wave] = loss;
    __syncthreads();
    if (threadIdx.x == 0) {
        float t = 0.f;
        #pragma unroll
        for (int w = 0; w < WAVES_PER_BLOCK; ++w) t += wsum[w];
        partial[blockIdx.x] = t;
    }
}

__global__ __launch_bounds__(256) void reduce_partials_kernel(
    const float* __restrict__ partial, int n, float* __restrict__ out, float scale)
{
    __shared__ float sm[4];
    float t = 0.f;
    for (int i = threadIdx.x; i < n; i += 256) t += partial[i];
    #pragma unroll
    for (int off = 32; off > 0; off >>= 1) t += __shfl_xor(t, off, 64);
    const int lane = threadIdx.x & 63;
    const int wave = threadIdx.x >> 6;
    if (lane == 0) sm[wave] = t;
    __syncthreads();
    if (threadIdx.x == 0) {
        out[0] = (sm[0] + sm[1] + sm[2] + sm[3]) * scale;
    }
}

extern "C" void kernel_launch(void* const* d_in, const int* in_sizes, int n_in,
                              void* d_out, int out_size, void* d_ws, size_t ws_size,
                              hipStream_t stream) {
    const int* context     = (const int*)d_in[0];
    const int* target      = (const int*)d_in[1];
    const int* neg_targets = (const int*)d_in[2];
    const float* W_in      = (const float*)d_in[3];
    const float* W_out     = (const float*)d_in[4];
    float* out = (float*)d_out;

    const int B = in_sizes[1];                               // 16384
    const int elems_per_block = 2 * WAVES_PER_BLOCK;         // 8
    const int nblocks = (B + elems_per_block - 1) / elems_per_block;  // 2048

    float* partial = (float*)d_ws;

    cbow_partial_kernel<<<nblocks, 256, 0, stream>>>(
        context, target, neg_targets, W_in, W_out, partial, B);

    reduce_partials_kernel<<<1, 256, 0, stream>>>(
        partial, nblocks, out, -1.0f / (float)B);
}